// Round 4
// baseline (1288.944 us; speedup 1.0000x reference)
//
#include <hip/hip_runtime.h>
#include <math.h>

#define NN 100000
#define NE 1600000
#define NB 391   // ceil(NN/256) dst-buckets of 256 nodes

typedef __attribute__((ext_vector_type(8))) short short8;
typedef __attribute__((ext_vector_type(4))) float f32x4;
union frag8 { short s[8]; short8 v; };

// split fp32 into bf16 hi (truncated) + bf16 lo (rounded residual)
__device__ __forceinline__ void split_bf16(float a, short& hi, short& lo) {
    unsigned u = __float_as_uint(a);
    unsigned hb = u & 0xffff0000u;
    hi = (short)(hb >> 16);
    float r = a - __uint_as_float(hb);
    unsigned lu = __float_as_uint(r);
    lo = (short)((lu + 0x7fff + ((lu >> 16) & 1)) >> 16);
}

// ---------------- bucket histogram (4096 edges/block, LDS-aggregated) ----------------
__global__ __launch_bounds__(256) void hist_k(const int* __restrict__ dst, int* __restrict__ hist, int e) {
    __shared__ int h[NB];
    int t = threadIdx.x;
    for (int i = t; i < NB; i += 256) h[i] = 0;
    __syncthreads();
    int base = blockIdx.x * 4096;
#pragma unroll
    for (int j = 0; j < 16; ++j) {
        int i = base + j * 256 + t;
        if (i < e) atomicAdd(&h[dst[i] >> 8], 1);
    }
    __syncthreads();
    for (int i = t; i < NB; i += 256) if (h[i]) atomicAdd(&hist[i], h[i]);
}

// ---------------- bucket scan (1 block, 512 thr) ----------------
__global__ __launch_bounds__(512) void bktscan_k(const int* __restrict__ hist,
                                                 int* __restrict__ boff, int* __restrict__ bcur) {
    __shared__ int wsum[8];
    int t = threadIdx.x, lane = t & 63, wid = t >> 6;
    int v = (t < NB) ? hist[t] : 0;
    int inc = v;
#pragma unroll
    for (int off = 1; off < 64; off <<= 1) {
        int tt = __shfl_up(inc, off);
        if (lane >= off) inc += tt;
    }
    if (lane == 63) wsum[wid] = inc;
    __syncthreads();
    int woff = 0;
    for (int w = 0; w < wid; ++w) woff += wsum[w];
    int excl = inc - v + woff;
    if (t < NB) { boff[t] = excl; bcur[t] = excl; }
    if (t == NB - 1) boff[NB] = excl + v;
}

// ---------------- partition edges into bucket-sorted (src,dst) pairs ----------------
__global__ __launch_bounds__(256) void part_k(const int* __restrict__ src, const int* __restrict__ dst,
                                              int* bcur, int2* __restrict__ pairs, int e) {
    int i = blockIdx.x * 256 + threadIdx.x;
    if (i < e) {
        int d = dst[i];
        int pos = atomicAdd(&bcur[d >> 8], 1);
        pairs[pos] = make_int2(src[i], d);
    }
}

// ---------------- per-bucket LDS degree count -> indeg, dinv (no global atomics) ----------------
__global__ __launch_bounds__(256) void cnt_k(const int2* __restrict__ pairs, const int* __restrict__ boff,
                                             int* __restrict__ indeg, float* __restrict__ dinv, int n) {
    __shared__ int cnt[256];
    int b = blockIdx.x, t = threadIdx.x;
    cnt[t] = 0;
    __syncthreads();
    int e0 = boff[b], e1 = boff[b + 1];
    for (int e = e0 + t; e < e1; e += 256) atomicAdd(&cnt[pairs[e].y & 255], 1);
    __syncthreads();
    int i = (b << 8) + t;
    if (i < n) {
        int c = cnt[t];
        indeg[i] = c;
        dinv[i] = 1.0f / sqrtf((float)(c + 1));
    }
}

// ---------------- parallel scan over indeg (3 kernels) ----------------
__global__ __launch_bounds__(256) void bsum_k(const int* __restrict__ indeg, int* __restrict__ bsum, int n) {
    __shared__ int wsum[4];
    int t = threadIdx.x;
    int base = blockIdx.x * 4096;
    int s = 0;
#pragma unroll
    for (int j = 0; j < 16; ++j) {
        int i = base + j * 256 + t;
        if (i < n) s += indeg[i];
    }
#pragma unroll
    for (int off = 32; off; off >>= 1) s += __shfl_down(s, off);
    if ((t & 63) == 0) wsum[t >> 6] = s;
    __syncthreads();
    if (t == 0) bsum[blockIdx.x] = wsum[0] + wsum[1] + wsum[2] + wsum[3];
}

__global__ __launch_bounds__(64) void bscan_k(const int* __restrict__ bsum, int* __restrict__ boff,
                                              int* __restrict__ rowptr_end, int nb) {
    int l = threadIdx.x;
    int v = (l < nb) ? bsum[l] : 0;
    int inc = v;
#pragma unroll
    for (int off = 1; off < 64; off <<= 1) {
        int t = __shfl_up(inc, off);
        if (l >= off) inc += t;
    }
    if (l < nb) boff[l] = inc - v;
    if (l == 63) *rowptr_end = inc;
}

__global__ __launch_bounds__(256) void scan2_k(const int* __restrict__ indeg, const int* __restrict__ boff,
                                               int* __restrict__ rowptr, int n) {
    __shared__ int wsum[4];
    int t = threadIdx.x, lane = t & 63, wid = t >> 6;
    int base = blockIdx.x * 4096 + t * 16;
    int d[16];
    int s = 0;
#pragma unroll
    for (int j = 0; j < 16; ++j) {
        int i = base + j;
        d[j] = (i < n) ? indeg[i] : 0;
        s += d[j];
    }
    int inc = s;
#pragma unroll
    for (int off = 1; off < 64; off <<= 1) {
        int tt = __shfl_up(inc, off);
        if (lane >= off) inc += tt;
    }
    if (lane == 63) wsum[wid] = inc;
    __syncthreads();
    int woff = 0;
    for (int w = 0; w < wid; ++w) woff += wsum[w];
    int excl = inc - s + woff + boff[blockIdx.x];
#pragma unroll
    for (int j = 0; j < 16; ++j) {
        int i = base + j;
        if (i < n) rowptr[i] = excl;
        excl += d[j];
    }
}

// ---------------- per-bucket CSR fill with LDS cursors ----------------
__global__ __launch_bounds__(256) void csrfill_k(const int2* __restrict__ pairs, const int* __restrict__ boff,
                                                 const int* __restrict__ rowptr, int* __restrict__ csr_src, int n) {
    __shared__ int lcur[256];
    int b = blockIdx.x, t = threadIdx.x;
    int i = (b << 8) + t;
    lcur[t] = (i < n) ? rowptr[i] : 0;
    __syncthreads();
    int e0 = boff[b], e1 = boff[b + 1];
    for (int e = e0 + t; e < e1; e += 256) {
        int2 p = pairs[e];
        int pos = atomicAdd(&lcur[p.y & 255], 1);
        csr_src[pos] = p.x;
    }
}

// ---------------- W pre-split (transposed bf16 hi/lo) ----------------
__global__ __launch_bounds__(256) void convw_k(const float* __restrict__ W0, const float* __restrict__ W1,
                                               const float* __restrict__ W2, const float* __restrict__ W3,
                                               short* __restrict__ wt) {
    int gid = blockIdx.x * 256 + threadIdx.x;
    if (gid >= 57344) return;
    const float* W;
    int elem, Ncols, hi_base;
    if (gid < 49152) {
        int w = gid >> 14;
        elem = gid & 16383;
        Ncols = 128;
        W = (w == 0) ? W0 : (w == 1) ? W1 : W2;
        hi_base = w * 32768;
    } else {
        elem = gid - 49152;
        Ncols = 64;
        W = W3;
        hi_base = 98304;
    }
    int k = elem / Ncols, ncol = elem % Ncols;
    short hi, lo;
    split_bf16(W[elem], hi, lo);
    int dstidx = ncol * 128 + k;
    wt[hi_base + dstidx] = hi;
    wt[hi_base + Ncols * 128 + dstidx] = lo;
}

// ---------------- MFMA GEMM with dinv-folded epilogue ----------------
// C[row] = (act(A) @ W)[row] * dinv[row]
template<int HOUT, bool RELU>
__global__ __launch_bounds__(256) void mfma_gemm_k(const float* __restrict__ A,
                                                   const short* __restrict__ wt_hi,
                                                   const short* __restrict__ wt_lo,
                                                   const float* __restrict__ dinv,
                                                   float* __restrict__ C, int n) {
    constexpr int NT = HOUT / 16;
    const int tid = threadIdx.x;
    const int wid = tid >> 6, lane = tid & 63;
    const int arow = blockIdx.x * 64 + wid * 16 + (lane & 15);
    const int khalf = lane >> 4;

    f32x4 acc[NT];
#pragma unroll
    for (int nt = 0; nt < NT; ++nt) acc[nt] = (f32x4){0.f, 0.f, 0.f, 0.f};

#pragma unroll
    for (int kc = 0; kc < 4; ++kc) {
        const int k0 = kc * 32 + khalf * 8;
        float4 a0 = make_float4(0.f, 0.f, 0.f, 0.f), a1 = a0;
        if (arow < n) {
            a0 = *(const float4*)(A + (size_t)arow * 128 + k0);
            a1 = *(const float4*)(A + (size_t)arow * 128 + k0 + 4);
        }
        if (RELU) {
            a0.x = fmaxf(a0.x, 0.f); a0.y = fmaxf(a0.y, 0.f);
            a0.z = fmaxf(a0.z, 0.f); a0.w = fmaxf(a0.w, 0.f);
            a1.x = fmaxf(a1.x, 0.f); a1.y = fmaxf(a1.y, 0.f);
            a1.z = fmaxf(a1.z, 0.f); a1.w = fmaxf(a1.w, 0.f);
        }
        frag8 ahi, alo;
        float av[8] = {a0.x, a0.y, a0.z, a0.w, a1.x, a1.y, a1.z, a1.w};
#pragma unroll
        for (int j = 0; j < 8; ++j) split_bf16(av[j], ahi.s[j], alo.s[j]);

#pragma unroll
        for (int nt = 0; nt < NT; ++nt) {
            const size_t bidx = (size_t)(nt * 16 + (lane & 15)) * 128 + k0;
            short8 bhi = *(const short8*)(wt_hi + bidx);
            short8 blo = *(const short8*)(wt_lo + bidx);
            acc[nt] = __builtin_amdgcn_mfma_f32_16x16x32_bf16(alo.v, bhi, acc[nt], 0, 0, 0);
            acc[nt] = __builtin_amdgcn_mfma_f32_16x16x32_bf16(ahi.v, blo, acc[nt], 0, 0, 0);
            acc[nt] = __builtin_amdgcn_mfma_f32_16x16x32_bf16(ahi.v, bhi, acc[nt], 0, 0, 0);
        }
    }

    const int rbase = blockIdx.x * 64 + wid * 16 + khalf * 4;
    const int col = lane & 15;
    float dv[4];
#pragma unroll
    for (int r = 0; r < 4; ++r) dv[r] = (rbase + r < n) ? dinv[rbase + r] : 0.f;
#pragma unroll
    for (int nt = 0; nt < NT; ++nt) {
#pragma unroll
        for (int r = 0; r < 4; ++r) {
            int row = rbase + r;
            if (row < n) C[(size_t)row * HOUT + nt * 16 + col] = acc[nt][r] * dv[r];
        }
    }
}

// ---------------- gather-aggregate with index prefetch + unroll-4 ----------------
// out[d] = dinv[d] * ( h'[d] + sum_{s in in(d)} h'[s] ) + bias,  h' = h*dinv pre-folded
template<int HOUT>
__global__ __launch_bounds__(256) void agg2_k(const float* __restrict__ tmp,
                                              const int* __restrict__ csr_src,
                                              const int* __restrict__ rowptr,
                                              const float* __restrict__ dinv,
                                              const float* __restrict__ bias,
                                              float* __restrict__ out, int n) {
    constexpr int LPN = HOUT / 4;
    int gid = blockIdx.x * 256 + threadIdx.x;
    int node = gid / LPN, l = gid % LPN;
    if (node >= n) return;

    const float dn = dinv[node];
    float4 bb = *(const float4*)(bias + l * 4);
    float4 acc = *(const float4*)(tmp + (size_t)node * HOUT + l * 4);

    int e = rowptr[node];
    const int end = rowptr[node + 1];
    while (e < end) {
        int m = end - e;
        if (m > LPN) m = LPN;
        int myidx = (e + l < end) ? csr_src[e + l] : 0;   // coalesced chunk prefetch
        int j = 0;
        for (; j + 4 <= m; j += 4) {
            int s0 = __shfl(myidx, j, LPN);
            int s1 = __shfl(myidx, j + 1, LPN);
            int s2 = __shfl(myidx, j + 2, LPN);
            int s3 = __shfl(myidx, j + 3, LPN);
            float4 v0 = *(const float4*)(tmp + (size_t)s0 * HOUT + l * 4);
            float4 v1 = *(const float4*)(tmp + (size_t)s1 * HOUT + l * 4);
            float4 v2 = *(const float4*)(tmp + (size_t)s2 * HOUT + l * 4);
            float4 v3 = *(const float4*)(tmp + (size_t)s3 * HOUT + l * 4);
            acc.x += (v0.x + v1.x) + (v2.x + v3.x);
            acc.y += (v0.y + v1.y) + (v2.y + v3.y);
            acc.z += (v0.z + v1.z) + (v2.z + v3.z);
            acc.w += (v0.w + v1.w) + (v2.w + v3.w);
        }
        for (; j < m; ++j) {
            int s0 = __shfl(myidx, j, LPN);
            float4 v0 = *(const float4*)(tmp + (size_t)s0 * HOUT + l * 4);
            acc.x += v0.x; acc.y += v0.y; acc.z += v0.z; acc.w += v0.w;
        }
        e += m;
    }
    float4 o;
    o.x = fmaf(acc.x, dn, bb.x);
    o.y = fmaf(acc.y, dn, bb.y);
    o.z = fmaf(acc.z, dn, bb.z);
    o.w = fmaf(acc.w, dn, bb.w);
    *(float4*)(out + (size_t)node * HOUT + l * 4) = o;
}

extern "C" void kernel_launch(void* const* d_in, const int* in_sizes, int n_in,
                              void* d_out, int out_size, void* d_ws, size_t ws_size,
                              hipStream_t stream) {
    const float* x    = (const float*)d_in[0];
    const int*   ei   = (const int*)d_in[1];
    const int*   srcp = ei;
    const int*   dstp = ei + NE;
    const float* W0 = (const float*)d_in[2]; const float* b0 = (const float*)d_in[3];
    const float* W1 = (const float*)d_in[4]; const float* b1 = (const float*)d_in[5];
    const float* W2 = (const float*)d_in[6]; const float* b2 = (const float*)d_in[7];
    const float* W3 = (const float*)d_in[8]; const float* b3 = (const float*)d_in[9];
    float* out = (float*)d_out;

    char* ws = (char*)d_ws;
    size_t off = 0;
    auto alloc = [&](size_t bytes) { void* p = ws + off; off = (off + bytes + 255) & ~(size_t)255; return p; };
    int*   hist    = (int*)alloc((size_t)NB * 4);
    int*   boff    = (int*)alloc((size_t)(NB + 1) * 4);
    int*   bcur    = (int*)alloc((size_t)NB * 4);
    int*   indeg   = (int*)alloc((size_t)NN * 4);
    float* dinv    = (float*)alloc((size_t)NN * 4);
    int*   rowptr  = (int*)alloc((size_t)(NN + 1) * 4);
    int*   bsum    = (int*)alloc(64 * 4);
    int*   bsoff   = (int*)alloc(64 * 4);
    int*   csr_src = (int*)alloc((size_t)NE * 4);
    short* wt      = (short*)alloc((size_t)114688 * 2);
    float* bufA    = (float*)alloc((size_t)NN * 128 * 4);
    float* bufB    = (float*)alloc((size_t)NN * 128 * 4);
    int2*  pairs   = (int2*)bufA;   // alias: pairs dead before first gemm writes bufA

    const int nblk_e4k  = (NE + 4095) / 4096;   // 391
    const int nblk_e    = (NE + 255) / 256;     // 6250
    const int nblk_scan = (NN + 4095) / 4096;   // 25
    const int nblk_g    = (NN + 63) / 64;       // 1563
    const int nblk_a128 = (int)(((size_t)NN * 32 + 255) / 256);
    const int nblk_a64  = (int)(((size_t)NN * 16 + 255) / 256);

    // ---- graph preprocessing: bucketed CSR build ----
    hipMemsetAsync(hist, 0, (size_t)NB * 4, stream);
    hist_k<<<nblk_e4k, 256, 0, stream>>>(dstp, hist, NE);
    bktscan_k<<<1, 512, 0, stream>>>(hist, boff, bcur);
    part_k<<<nblk_e, 256, 0, stream>>>(srcp, dstp, bcur, pairs, NE);
    cnt_k<<<NB, 256, 0, stream>>>(pairs, boff, indeg, dinv, NN);
    bsum_k<<<nblk_scan, 256, 0, stream>>>(indeg, bsum, NN);
    bscan_k<<<1, 64, 0, stream>>>(bsum, bsoff, rowptr + NN, nblk_scan);
    scan2_k<<<nblk_scan, 256, 0, stream>>>(indeg, bsoff, rowptr, NN);
    csrfill_k<<<NB, 256, 0, stream>>>(pairs, boff, rowptr, csr_src, NN);
    convw_k<<<(57344 + 255) / 256, 256, 0, stream>>>(W0, W1, W2, W3, wt);

    const short* w0h = wt,          *w0l = wt + 16384;
    const short* w1h = wt + 32768,  *w1l = wt + 49152;
    const short* w2h = wt + 65536,  *w2l = wt + 81920;
    const short* w3h = wt + 98304,  *w3l = wt + 106496;

    // ---- layer 0 ----
    mfma_gemm_k<128, false><<<nblk_g, 256, 0, stream>>>(x, w0h, w0l, dinv, bufA, NN);
    agg2_k<128><<<nblk_a128, 256, 0, stream>>>(bufA, csr_src, rowptr, dinv, b0, bufB, NN);
    // ---- layer 1 ----
    mfma_gemm_k<128, true><<<nblk_g, 256, 0, stream>>>(bufB, w1h, w1l, dinv, bufA, NN);
    agg2_k<128><<<nblk_a128, 256, 0, stream>>>(bufA, csr_src, rowptr, dinv, b1, bufB, NN);
    // ---- layer 2 ----
    mfma_gemm_k<128, true><<<nblk_g, 256, 0, stream>>>(bufB, w2h, w2l, dinv, bufA, NN);
    agg2_k<128><<<nblk_a128, 256, 0, stream>>>(bufA, csr_src, rowptr, dinv, b2, bufB, NN);
    // ---- layer 3 ----
    mfma_gemm_k<64, true><<<nblk_g, 256, 0, stream>>>(bufB, w3h, w3l, dinv, bufA, NN);
    agg2_k<64><<<nblk_a64, 256, 0, stream>>>(bufA, csr_src, rowptr, dinv, b3, out, NN);
}

// Round 5
// 742.226 us; speedup vs baseline: 1.7366x; 1.7366x over previous
//
#include <hip/hip_runtime.h>
#include <math.h>

#define NN 100000
#define NE 1600000
#define NB 391   // ceil(NN/256) dst-buckets of 256 nodes

typedef __attribute__((ext_vector_type(8))) short short8;
typedef __attribute__((ext_vector_type(4))) float f32x4;
union frag8 { short s[8]; short8 v; };

// split fp32 into bf16 hi (truncated) + bf16 lo (rounded residual)
__device__ __forceinline__ void split_bf16(float a, short& hi, short& lo) {
    unsigned u = __float_as_uint(a);
    unsigned hb = u & 0xffff0000u;
    hi = (short)(hb >> 16);
    float r = a - __uint_as_float(hb);
    unsigned lu = __float_as_uint(r);
    lo = (short)((lu + 0x7fff + ((lu >> 16) & 1)) >> 16);
}

// ---------------- bucket histogram (4096 edges/block, LDS-aggregated) ----------------
__global__ __launch_bounds__(256) void hist_k(const int* __restrict__ dst, int* __restrict__ hist, int e) {
    __shared__ int h[NB];
    int t = threadIdx.x;
    for (int i = t; i < NB; i += 256) h[i] = 0;
    __syncthreads();
    int base = blockIdx.x * 4096;
#pragma unroll
    for (int j = 0; j < 16; ++j) {
        int i = base + j * 256 + t;
        if (i < e) atomicAdd(&h[dst[i] >> 8], 1);
    }
    __syncthreads();
    for (int i = t; i < NB; i += 256) if (h[i]) atomicAdd(&hist[i], h[i]);
}

// ---------------- bucket scan (1 block, 512 thr) ----------------
__global__ __launch_bounds__(512) void bktscan_k(const int* __restrict__ hist,
                                                 int* __restrict__ boff, int* __restrict__ bcur) {
    __shared__ int wsum[8];
    int t = threadIdx.x, lane = t & 63, wid = t >> 6;
    int v = (t < NB) ? hist[t] : 0;
    int inc = v;
#pragma unroll
    for (int off = 1; off < 64; off <<= 1) {
        int tt = __shfl_up(inc, off);
        if (lane >= off) inc += tt;
    }
    if (lane == 63) wsum[wid] = inc;
    __syncthreads();
    int woff = 0;
    for (int w = 0; w < wid; ++w) woff += wsum[w];
    int excl = inc - v + woff;
    if (t < NB) { boff[t] = excl; bcur[t] = excl; }
    if (t == NB - 1) boff[NB] = excl + v;
}

// ---------------- partition via block-local chunk reservation ----------------
// one global atomicAdd per (block,bucket) instead of per edge
__global__ __launch_bounds__(256) void part2_k(const int* __restrict__ src, const int* __restrict__ dst,
                                               int* bcur, int2* __restrict__ pairs, int e) {
    __shared__ int lhist[NB];
    __shared__ int lbase[NB];
    int t = threadIdx.x;
    for (int i = t; i < NB; i += 256) lhist[i] = 0;
    __syncthreads();
    int e0 = blockIdx.x * 4096;
    int sreg[16], dreg[16];
#pragma unroll
    for (int j = 0; j < 16; ++j) {
        int i = e0 + j * 256 + t;
        if (i < e) {
            sreg[j] = src[i];
            dreg[j] = dst[i];
            atomicAdd(&lhist[dreg[j] >> 8], 1);
        } else dreg[j] = -1;
    }
    __syncthreads();
    for (int i = t; i < NB; i += 256) {
        int c = lhist[i];
        lbase[i] = c ? atomicAdd(&bcur[i], c) : 0;   // reserve chunk in bucket region
        lhist[i] = 0;                                 // becomes local cursor
    }
    __syncthreads();
#pragma unroll
    for (int j = 0; j < 16; ++j) {
        if (dreg[j] >= 0) {
            int b = dreg[j] >> 8;
            int pos = lbase[b] + atomicAdd(&lhist[b], 1);
            pairs[pos] = make_int2(sreg[j], dreg[j]);
        }
    }
}

// ---------------- per-bucket: count, dinv, rowptr (LDS scan; no global scan needed) ----------------
__global__ __launch_bounds__(256) void cnt2_k(const int2* __restrict__ pairs, const int* __restrict__ boff,
                                              float* __restrict__ dinv, int* __restrict__ rowptr, int n) {
    __shared__ int cnt[256];
    __shared__ int wsum[4];
    int b = blockIdx.x, t = threadIdx.x;
    cnt[t] = 0;
    __syncthreads();
    int e0 = boff[b], e1 = boff[b + 1];
    for (int e = e0 + t; e < e1; e += 256) atomicAdd(&cnt[pairs[e].y & 255], 1);
    __syncthreads();
    int c = cnt[t];
    int lane = t & 63, wid = t >> 6;
    int inc = c;
#pragma unroll
    for (int off = 1; off < 64; off <<= 1) {
        int tt = __shfl_up(inc, off);
        if (lane >= off) inc += tt;
    }
    if (lane == 63) wsum[wid] = inc;
    __syncthreads();
    int woff = 0;
    for (int w = 0; w < wid; ++w) woff += wsum[w];
    int excl = inc - c + woff + e0;   // global CSR offset: bucket base + in-bucket exclusive scan
    int i = (b << 8) + t;
    if (i < n) {
        rowptr[i] = excl;
        dinv[i] = 1.0f / sqrtf((float)(c + 1));
    }
    if (b == NB - 1 && t == 255) rowptr[n] = e1;
}

// ---------------- per-bucket CSR fill with LDS cursors ----------------
__global__ __launch_bounds__(256) void csrfill_k(const int2* __restrict__ pairs, const int* __restrict__ boff,
                                                 const int* __restrict__ rowptr, int* __restrict__ csr_src, int n) {
    __shared__ int lcur[256];
    int b = blockIdx.x, t = threadIdx.x;
    int i = (b << 8) + t;
    lcur[t] = (i < n) ? rowptr[i] : 0;
    __syncthreads();
    int e0 = boff[b], e1 = boff[b + 1];
    for (int e = e0 + t; e < e1; e += 256) {
        int2 p = pairs[e];
        int pos = atomicAdd(&lcur[p.y & 255], 1);
        csr_src[pos] = p.x;
    }
}

// ---------------- W pre-split (transposed bf16 hi/lo) ----------------
__global__ __launch_bounds__(256) void convw_k(const float* __restrict__ W0, const float* __restrict__ W1,
                                               const float* __restrict__ W2, const float* __restrict__ W3,
                                               short* __restrict__ wt) {
    int gid = blockIdx.x * 256 + threadIdx.x;
    if (gid >= 57344) return;
    const float* W;
    int elem, Ncols, hi_base;
    if (gid < 49152) {
        int w = gid >> 14;
        elem = gid & 16383;
        Ncols = 128;
        W = (w == 0) ? W0 : (w == 1) ? W1 : W2;
        hi_base = w * 32768;
    } else {
        elem = gid - 49152;
        Ncols = 64;
        W = W3;
        hi_base = 98304;
    }
    int k = elem / Ncols, ncol = elem % Ncols;
    short hi, lo;
    split_bf16(W[elem], hi, lo);
    int dstidx = ncol * 128 + k;
    wt[hi_base + dstidx] = hi;
    wt[hi_base + Ncols * 128 + dstidx] = lo;
}

// ---------------- MFMA GEMM with dinv-folded epilogue ----------------
template<int HOUT, bool RELU>
__global__ __launch_bounds__(256) void mfma_gemm_k(const float* __restrict__ A,
                                                   const short* __restrict__ wt_hi,
                                                   const short* __restrict__ wt_lo,
                                                   const float* __restrict__ dinv,
                                                   float* __restrict__ C, int n) {
    constexpr int NT = HOUT / 16;
    const int tid = threadIdx.x;
    const int wid = tid >> 6, lane = tid & 63;
    const int arow = blockIdx.x * 64 + wid * 16 + (lane & 15);
    const int khalf = lane >> 4;

    f32x4 acc[NT];
#pragma unroll
    for (int nt = 0; nt < NT; ++nt) acc[nt] = (f32x4){0.f, 0.f, 0.f, 0.f};

#pragma unroll
    for (int kc = 0; kc < 4; ++kc) {
        const int k0 = kc * 32 + khalf * 8;
        float4 a0 = make_float4(0.f, 0.f, 0.f, 0.f), a1 = a0;
        if (arow < n) {
            a0 = *(const float4*)(A + (size_t)arow * 128 + k0);
            a1 = *(const float4*)(A + (size_t)arow * 128 + k0 + 4);
        }
        if (RELU) {
            a0.x = fmaxf(a0.x, 0.f); a0.y = fmaxf(a0.y, 0.f);
            a0.z = fmaxf(a0.z, 0.f); a0.w = fmaxf(a0.w, 0.f);
            a1.x = fmaxf(a1.x, 0.f); a1.y = fmaxf(a1.y, 0.f);
            a1.z = fmaxf(a1.z, 0.f); a1.w = fmaxf(a1.w, 0.f);
        }
        frag8 ahi, alo;
        float av[8] = {a0.x, a0.y, a0.z, a0.w, a1.x, a1.y, a1.z, a1.w};
#pragma unroll
        for (int j = 0; j < 8; ++j) split_bf16(av[j], ahi.s[j], alo.s[j]);

#pragma unroll
        for (int nt = 0; nt < NT; ++nt) {
            const size_t bidx = (size_t)(nt * 16 + (lane & 15)) * 128 + k0;
            short8 bhi = *(const short8*)(wt_hi + bidx);
            short8 blo = *(const short8*)(wt_lo + bidx);
            acc[nt] = __builtin_amdgcn_mfma_f32_16x16x32_bf16(alo.v, bhi, acc[nt], 0, 0, 0);
            acc[nt] = __builtin_amdgcn_mfma_f32_16x16x32_bf16(ahi.v, blo, acc[nt], 0, 0, 0);
            acc[nt] = __builtin_amdgcn_mfma_f32_16x16x32_bf16(ahi.v, bhi, acc[nt], 0, 0, 0);
        }
    }

    const int rbase = blockIdx.x * 64 + wid * 16 + khalf * 4;
    const int col = lane & 15;
    float dv[4];
#pragma unroll
    for (int r = 0; r < 4; ++r) dv[r] = (rbase + r < n) ? dinv[rbase + r] : 0.f;
#pragma unroll
    for (int nt = 0; nt < NT; ++nt) {
#pragma unroll
        for (int r = 0; r < 4; ++r) {
            int row = rbase + r;
            if (row < n) C[(size_t)row * HOUT + nt * 16 + col] = acc[nt][r] * dv[r];
        }
    }
}

// ---------------- gather-aggregate with index prefetch + unroll-4 ----------------
template<int HOUT>
__global__ __launch_bounds__(256) void agg2_k(const float* __restrict__ tmp,
                                              const int* __restrict__ csr_src,
                                              const int* __restrict__ rowptr,
                                              const float* __restrict__ dinv,
                                              const float* __restrict__ bias,
                                              float* __restrict__ out, int n) {
    constexpr int LPN = HOUT / 4;
    int gid = blockIdx.x * 256 + threadIdx.x;
    int node = gid / LPN, l = gid % LPN;
    if (node >= n) return;

    const float dn = dinv[node];
    float4 bb = *(const float4*)(bias + l * 4);
    float4 acc = *(const float4*)(tmp + (size_t)node * HOUT + l * 4);

    int e = rowptr[node];
    const int end = rowptr[node + 1];
    while (e < end) {
        int m = end - e;
        if (m > LPN) m = LPN;
        int myidx = (e + l < end) ? csr_src[e + l] : 0;
        int j = 0;
        for (; j + 4 <= m; j += 4) {
            int s0 = __shfl(myidx, j, LPN);
            int s1 = __shfl(myidx, j + 1, LPN);
            int s2 = __shfl(myidx, j + 2, LPN);
            int s3 = __shfl(myidx, j + 3, LPN);
            float4 v0 = *(const float4*)(tmp + (size_t)s0 * HOUT + l * 4);
            float4 v1 = *(const float4*)(tmp + (size_t)s1 * HOUT + l * 4);
            float4 v2 = *(const float4*)(tmp + (size_t)s2 * HOUT + l * 4);
            float4 v3 = *(const float4*)(tmp + (size_t)s3 * HOUT + l * 4);
            acc.x += (v0.x + v1.x) + (v2.x + v3.x);
            acc.y += (v0.y + v1.y) + (v2.y + v3.y);
            acc.z += (v0.z + v1.z) + (v2.z + v3.z);
            acc.w += (v0.w + v1.w) + (v2.w + v3.w);
        }
        for (; j < m; ++j) {
            int s0 = __shfl(myidx, j, LPN);
            float4 v0 = *(const float4*)(tmp + (size_t)s0 * HOUT + l * 4);
            acc.x += v0.x; acc.y += v0.y; acc.z += v0.z; acc.w += v0.w;
        }
        e += m;
    }
    float4 o;
    o.x = fmaf(acc.x, dn, bb.x);
    o.y = fmaf(acc.y, dn, bb.y);
    o.z = fmaf(acc.z, dn, bb.z);
    o.w = fmaf(acc.w, dn, bb.w);
    *(float4*)(out + (size_t)node * HOUT + l * 4) = o;
}

extern "C" void kernel_launch(void* const* d_in, const int* in_sizes, int n_in,
                              void* d_out, int out_size, void* d_ws, size_t ws_size,
                              hipStream_t stream) {
    const float* x    = (const float*)d_in[0];
    const int*   ei   = (const int*)d_in[1];
    const int*   srcp = ei;
    const int*   dstp = ei + NE;
    const float* W0 = (const float*)d_in[2]; const float* b0 = (const float*)d_in[3];
    const float* W1 = (const float*)d_in[4]; const float* b1 = (const float*)d_in[5];
    const float* W2 = (const float*)d_in[6]; const float* b2 = (const float*)d_in[7];
    const float* W3 = (const float*)d_in[8]; const float* b3 = (const float*)d_in[9];
    float* out = (float*)d_out;

    char* ws = (char*)d_ws;
    size_t off = 0;
    auto alloc = [&](size_t bytes) { void* p = ws + off; off = (off + bytes + 255) & ~(size_t)255; return p; };
    int*   hist    = (int*)alloc((size_t)NB * 4);
    int*   boff    = (int*)alloc((size_t)(NB + 1) * 4);
    int*   bcur    = (int*)alloc((size_t)NB * 4);
    float* dinv    = (float*)alloc((size_t)NN * 4);
    int*   rowptr  = (int*)alloc((size_t)(NN + 1) * 4);
    int*   csr_src = (int*)alloc((size_t)NE * 4);
    short* wt      = (short*)alloc((size_t)114688 * 2);
    float* bufA    = (float*)alloc((size_t)NN * 128 * 4);
    float* bufB    = (float*)alloc((size_t)NN * 128 * 4);
    int2*  pairs   = (int2*)bufA;   // alias: pairs dead before first gemm writes bufA

    const int nblk_e4k  = (NE + 4095) / 4096;   // 391
    const int nblk_g    = (NN + 63) / 64;       // 1563
    const int nblk_a128 = (int)(((size_t)NN * 32 + 255) / 256);
    const int nblk_a64  = (int)(((size_t)NN * 16 + 255) / 256);

    // ---- graph preprocessing: bucketed CSR build ----
    hipMemsetAsync(hist, 0, (size_t)NB * 4, stream);
    hist_k<<<nblk_e4k, 256, 0, stream>>>(dstp, hist, NE);
    bktscan_k<<<1, 512, 0, stream>>>(hist, boff, bcur);
    part2_k<<<nblk_e4k, 256, 0, stream>>>(srcp, dstp, bcur, pairs, NE);
    cnt2_k<<<NB, 256, 0, stream>>>(pairs, boff, dinv, rowptr, NN);
    csrfill_k<<<NB, 256, 0, stream>>>(pairs, boff, rowptr, csr_src, NN);
    convw_k<<<(57344 + 255) / 256, 256, 0, stream>>>(W0, W1, W2, W3, wt);

    const short* w0h = wt,          *w0l = wt + 16384;
    const short* w1h = wt + 32768,  *w1l = wt + 49152;
    const short* w2h = wt + 65536,  *w2l = wt + 81920;
    const short* w3h = wt + 98304,  *w3l = wt + 106496;

    // ---- layer 0 ----
    mfma_gemm_k<128, false><<<nblk_g, 256, 0, stream>>>(x, w0h, w0l, dinv, bufA, NN);
    agg2_k<128><<<nblk_a128, 256, 0, stream>>>(bufA, csr_src, rowptr, dinv, b0, bufB, NN);
    // ---- layer 1 ----
    mfma_gemm_k<128, true><<<nblk_g, 256, 0, stream>>>(bufB, w1h, w1l, dinv, bufA, NN);
    agg2_k<128><<<nblk_a128, 256, 0, stream>>>(bufA, csr_src, rowptr, dinv, b1, bufB, NN);
    // ---- layer 2 ----
    mfma_gemm_k<128, true><<<nblk_g, 256, 0, stream>>>(bufB, w2h, w2l, dinv, bufA, NN);
    agg2_k<128><<<nblk_a128, 256, 0, stream>>>(bufA, csr_src, rowptr, dinv, b2, bufB, NN);
    // ---- layer 3 ----
    mfma_gemm_k<64, true><<<nblk_g, 256, 0, stream>>>(bufB, w3h, w3l, dinv, bufA, NN);
    agg2_k<64><<<nblk_a64, 256, 0, stream>>>(bufA, csr_src, rowptr, dinv, b3, out, NN);
}

// Round 6
// 695.317 us; speedup vs baseline: 1.8538x; 1.0675x over previous
//
#include <hip/hip_runtime.h>
#include <math.h>

#define NN 100000
#define NE 1600000
#define NB 391   // ceil(NN/256) dst-buckets of 256 nodes

typedef __attribute__((ext_vector_type(8))) short short8;
typedef __attribute__((ext_vector_type(4))) float f32x4;
union frag8 { short s[8]; short8 v; };

// split fp32 into bf16 hi (truncated) + bf16 lo (rounded residual)
__device__ __forceinline__ void split_bf16(float a, short& hi, short& lo) {
    unsigned u = __float_as_uint(a);
    unsigned hb = u & 0xffff0000u;
    hi = (short)(hb >> 16);
    float r = a - __uint_as_float(hb);
    unsigned lu = __float_as_uint(r);
    lo = (short)((lu + 0x7fff + ((lu >> 16) & 1)) >> 16);
}

// ---------------- bucket histogram ----------------
__global__ __launch_bounds__(256) void hist_k(const int* __restrict__ dst, int* __restrict__ hist, int e) {
    __shared__ int h[NB];
    int t = threadIdx.x;
    for (int i = t; i < NB; i += 256) h[i] = 0;
    __syncthreads();
    int base = blockIdx.x * 4096;
#pragma unroll
    for (int j = 0; j < 16; ++j) {
        int i = base + j * 256 + t;
        if (i < e) atomicAdd(&h[dst[i] >> 8], 1);
    }
    __syncthreads();
    for (int i = t; i < NB; i += 256) if (h[i]) atomicAdd(&hist[i], h[i]);
}

// ---------------- bucket scan ----------------
__global__ __launch_bounds__(512) void bktscan_k(const int* __restrict__ hist,
                                                 int* __restrict__ boff, int* __restrict__ bcur) {
    __shared__ int wsum[8];
    int t = threadIdx.x, lane = t & 63, wid = t >> 6;
    int v = (t < NB) ? hist[t] : 0;
    int inc = v;
#pragma unroll
    for (int off = 1; off < 64; off <<= 1) {
        int tt = __shfl_up(inc, off);
        if (lane >= off) inc += tt;
    }
    if (lane == 63) wsum[wid] = inc;
    __syncthreads();
    int woff = 0;
    for (int w = 0; w < wid; ++w) woff += wsum[w];
    int excl = inc - v + woff;
    if (t < NB) { boff[t] = excl; bcur[t] = excl; }
    if (t == NB - 1) boff[NB] = excl + v;
}

// ---------------- partition via block-local chunk reservation ----------------
__global__ __launch_bounds__(256) void part2_k(const int* __restrict__ src, const int* __restrict__ dst,
                                               int* bcur, int2* __restrict__ pairs, int e) {
    __shared__ int lhist[NB];
    __shared__ int lbase[NB];
    int t = threadIdx.x;
    for (int i = t; i < NB; i += 256) lhist[i] = 0;
    __syncthreads();
    int e0 = blockIdx.x * 4096;
    int sreg[16], dreg[16];
#pragma unroll
    for (int j = 0; j < 16; ++j) {
        int i = e0 + j * 256 + t;
        if (i < e) {
            sreg[j] = src[i];
            dreg[j] = dst[i];
            atomicAdd(&lhist[dreg[j] >> 8], 1);
        } else dreg[j] = -1;
    }
    __syncthreads();
    for (int i = t; i < NB; i += 256) {
        int c = lhist[i];
        lbase[i] = c ? atomicAdd(&bcur[i], c) : 0;
        lhist[i] = 0;
    }
    __syncthreads();
#pragma unroll
    for (int j = 0; j < 16; ++j) {
        if (dreg[j] >= 0) {
            int b = dreg[j] >> 8;
            int pos = lbase[b] + atomicAdd(&lhist[b], 1);
            pairs[pos] = make_int2(sreg[j], dreg[j]);
        }
    }
}

// ---------------- per-bucket: count, dinv, rowptr ----------------
__global__ __launch_bounds__(256) void cnt2_k(const int2* __restrict__ pairs, const int* __restrict__ boff,
                                              float* __restrict__ dinv, int* __restrict__ rowptr, int n) {
    __shared__ int cnt[256];
    __shared__ int wsum[4];
    int b = blockIdx.x, t = threadIdx.x;
    cnt[t] = 0;
    __syncthreads();
    int e0 = boff[b], e1 = boff[b + 1];
    for (int e = e0 + t; e < e1; e += 256) atomicAdd(&cnt[pairs[e].y & 255], 1);
    __syncthreads();
    int c = cnt[t];
    int lane = t & 63, wid = t >> 6;
    int inc = c;
#pragma unroll
    for (int off = 1; off < 64; off <<= 1) {
        int tt = __shfl_up(inc, off);
        if (lane >= off) inc += tt;
    }
    if (lane == 63) wsum[wid] = inc;
    __syncthreads();
    int woff = 0;
    for (int w = 0; w < wid; ++w) woff += wsum[w];
    int excl = inc - c + woff + e0;
    int i = (b << 8) + t;
    if (i < n) {
        rowptr[i] = excl;
        dinv[i] = 1.0f / sqrtf((float)(c + 1));
    }
    if (b == NB - 1 && t == 255) rowptr[n] = e1;
}

// ---------------- per-bucket CSR fill ----------------
__global__ __launch_bounds__(256) void csrfill_k(const int2* __restrict__ pairs, const int* __restrict__ boff,
                                                 const int* __restrict__ rowptr, int* __restrict__ csr_src, int n) {
    __shared__ int lcur[256];
    int b = blockIdx.x, t = threadIdx.x;
    int i = (b << 8) + t;
    lcur[t] = (i < n) ? rowptr[i] : 0;
    __syncthreads();
    int e0 = boff[b], e1 = boff[b + 1];
    for (int e = e0 + t; e < e1; e += 256) {
        int2 p = pairs[e];
        int pos = atomicAdd(&lcur[p.y & 255], 1);
        csr_src[pos] = p.x;
    }
}

// ---------------- W pre-split (transposed bf16 hi/lo) ----------------
__global__ __launch_bounds__(256) void convw_k(const float* __restrict__ W0, const float* __restrict__ W1,
                                               const float* __restrict__ W2, const float* __restrict__ W3,
                                               short* __restrict__ wt) {
    int gid = blockIdx.x * 256 + threadIdx.x;
    if (gid >= 57344) return;
    const float* W;
    int elem, Ncols, hi_base;
    if (gid < 49152) {
        int w = gid >> 14;
        elem = gid & 16383;
        Ncols = 128;
        W = (w == 0) ? W0 : (w == 1) ? W1 : W2;
        hi_base = w * 32768;
    } else {
        elem = gid - 49152;
        Ncols = 64;
        W = W3;
        hi_base = 98304;
    }
    int k = elem / Ncols, ncol = elem % Ncols;
    short hi, lo;
    split_bf16(W[elem], hi, lo);
    int dstidx = ncol * 128 + k;
    wt[hi_base + dstidx] = hi;
    wt[hi_base + Ncols * 128 + dstidx] = lo;
}

// ---------------- MFMA GEMM (layer 0): C = (x @ W)·dinv ----------------
__global__ __launch_bounds__(256) void mfma_gemm_k(const float* __restrict__ A,
                                                   const short* __restrict__ wt_hi,
                                                   const short* __restrict__ wt_lo,
                                                   const float* __restrict__ dinv,
                                                   float* __restrict__ C, int n) {
    constexpr int NT = 8;
    const int tid = threadIdx.x;
    const int wid = tid >> 6, lane = tid & 63;
    const int arow = blockIdx.x * 64 + wid * 16 + (lane & 15);
    const int khalf = lane >> 4;

    f32x4 acc[NT];
#pragma unroll
    for (int nt = 0; nt < NT; ++nt) acc[nt] = (f32x4){0.f, 0.f, 0.f, 0.f};

#pragma unroll
    for (int kc = 0; kc < 4; ++kc) {
        const int k0 = kc * 32 + khalf * 8;
        float4 a0 = make_float4(0.f, 0.f, 0.f, 0.f), a1 = a0;
        if (arow < n) {
            a0 = *(const float4*)(A + (size_t)arow * 128 + k0);
            a1 = *(const float4*)(A + (size_t)arow * 128 + k0 + 4);
        }
        frag8 ahi, alo;
        float av[8] = {a0.x, a0.y, a0.z, a0.w, a1.x, a1.y, a1.z, a1.w};
#pragma unroll
        for (int j = 0; j < 8; ++j) split_bf16(av[j], ahi.s[j], alo.s[j]);

#pragma unroll
        for (int nt = 0; nt < NT; ++nt) {
            const size_t bidx = (size_t)(nt * 16 + (lane & 15)) * 128 + k0;
            short8 bhi = *(const short8*)(wt_hi + bidx);
            short8 blo = *(const short8*)(wt_lo + bidx);
            acc[nt] = __builtin_amdgcn_mfma_f32_16x16x32_bf16(alo.v, bhi, acc[nt], 0, 0, 0);
            acc[nt] = __builtin_amdgcn_mfma_f32_16x16x32_bf16(ahi.v, blo, acc[nt], 0, 0, 0);
            acc[nt] = __builtin_amdgcn_mfma_f32_16x16x32_bf16(ahi.v, bhi, acc[nt], 0, 0, 0);
        }
    }

    const int rbase = blockIdx.x * 64 + wid * 16 + khalf * 4;
    const int col = lane & 15;
    float dv[4];
#pragma unroll
    for (int r = 0; r < 4; ++r) dv[r] = (rbase + r < n) ? dinv[rbase + r] : 0.f;
#pragma unroll
    for (int nt = 0; nt < NT; ++nt) {
#pragma unroll
        for (int r = 0; r < 4; ++r) {
            int row = rbase + r;
            if (row < n) C[(size_t)row * 128 + nt * 16 + col] = acc[nt][r] * dv[r];
        }
    }
}

// ---------------- FUSED: agg(tmp) + bias + ReLU -> GEMM W_next -> ·dinv -> C ----------------
// phase 1: 64 nodes aggregated into LDS; phase 2: split-bf16 MFMA from LDS
template<int HOUT>
__global__ __launch_bounds__(256) void fused_k(const float* __restrict__ tmp,
                                               const int* __restrict__ csr_src,
                                               const int* __restrict__ rowptr,
                                               const float* __restrict__ dinv,
                                               const float* __restrict__ bias,
                                               const short* __restrict__ wt_hi,
                                               const short* __restrict__ wt_lo,
                                               float* __restrict__ C, int n) {
    constexpr int NT = HOUT / 16;
    __shared__ float As[64][132];   // +4 pad: 16B-aligned rows, 2-way LDS conflict max
    const int t = threadIdx.x;
    const int row0 = blockIdx.x * 64;

    // ---- phase 1: aggregate 8 nodes per pass (32 lanes each), 8 passes ----
    {
        const int l = t & 31;
        const int sub = t >> 5;
        float4 bb = *(const float4*)(bias + l * 4);
#pragma unroll
        for (int it = 0; it < 8; ++it) {
            int node = row0 + it * 8 + sub;
            float4 acc = make_float4(0.f, 0.f, 0.f, 0.f);
            if (node < n) {
                float dn = dinv[node];
                acc = *(const float4*)(tmp + (size_t)node * 128 + l * 4);
                int e = rowptr[node];
                const int end = rowptr[node + 1];
                while (e < end) {
                    int m = end - e;
                    if (m > 32) m = 32;
                    int myidx = (e + l < end) ? csr_src[e + l] : 0;
                    int j = 0;
                    for (; j + 4 <= m; j += 4) {
                        int s0 = __shfl(myidx, j, 32);
                        int s1 = __shfl(myidx, j + 1, 32);
                        int s2 = __shfl(myidx, j + 2, 32);
                        int s3 = __shfl(myidx, j + 3, 32);
                        float4 v0 = *(const float4*)(tmp + (size_t)s0 * 128 + l * 4);
                        float4 v1 = *(const float4*)(tmp + (size_t)s1 * 128 + l * 4);
                        float4 v2 = *(const float4*)(tmp + (size_t)s2 * 128 + l * 4);
                        float4 v3 = *(const float4*)(tmp + (size_t)s3 * 128 + l * 4);
                        acc.x += (v0.x + v1.x) + (v2.x + v3.x);
                        acc.y += (v0.y + v1.y) + (v2.y + v3.y);
                        acc.z += (v0.z + v1.z) + (v2.z + v3.z);
                        acc.w += (v0.w + v1.w) + (v2.w + v3.w);
                    }
                    for (; j < m; ++j) {
                        int s0 = __shfl(myidx, j, 32);
                        float4 v0 = *(const float4*)(tmp + (size_t)s0 * 128 + l * 4);
                        acc.x += v0.x; acc.y += v0.y; acc.z += v0.z; acc.w += v0.w;
                    }
                    e += m;
                }
                acc.x = fmaxf(fmaf(acc.x, dn, bb.x), 0.f);
                acc.y = fmaxf(fmaf(acc.y, dn, bb.y), 0.f);
                acc.z = fmaxf(fmaf(acc.z, dn, bb.z), 0.f);
                acc.w = fmaxf(fmaf(acc.w, dn, bb.w), 0.f);
            }
            *(float4*)&As[it * 8 + sub][l * 4] = acc;
        }
    }
    __syncthreads();

    // ---- phase 2: MFMA from LDS ----
    const int wid = t >> 6, lane = t & 63;
    const int arow_l = wid * 16 + (lane & 15);
    const int khalf = lane >> 4;

    f32x4 acc[NT];
#pragma unroll
    for (int nt = 0; nt < NT; ++nt) acc[nt] = (f32x4){0.f, 0.f, 0.f, 0.f};

#pragma unroll
    for (int kc = 0; kc < 4; ++kc) {
        const int k0 = kc * 32 + khalf * 8;
        float4 a0 = *(const float4*)&As[arow_l][k0];
        float4 a1 = *(const float4*)&As[arow_l][k0 + 4];
        frag8 ahi, alo;
        float av[8] = {a0.x, a0.y, a0.z, a0.w, a1.x, a1.y, a1.z, a1.w};
#pragma unroll
        for (int j = 0; j < 8; ++j) split_bf16(av[j], ahi.s[j], alo.s[j]);

#pragma unroll
        for (int nt = 0; nt < NT; ++nt) {
            const size_t bidx = (size_t)(nt * 16 + (lane & 15)) * 128 + k0;
            short8 bhi = *(const short8*)(wt_hi + bidx);
            short8 blo = *(const short8*)(wt_lo + bidx);
            acc[nt] = __builtin_amdgcn_mfma_f32_16x16x32_bf16(alo.v, bhi, acc[nt], 0, 0, 0);
            acc[nt] = __builtin_amdgcn_mfma_f32_16x16x32_bf16(ahi.v, blo, acc[nt], 0, 0, 0);
            acc[nt] = __builtin_amdgcn_mfma_f32_16x16x32_bf16(ahi.v, bhi, acc[nt], 0, 0, 0);
        }
    }

    const int rbase = row0 + wid * 16 + khalf * 4;
    const int col = lane & 15;
    float dv[4];
#pragma unroll
    for (int r = 0; r < 4; ++r) dv[r] = (rbase + r < n) ? dinv[rbase + r] : 0.f;
#pragma unroll
    for (int nt = 0; nt < NT; ++nt) {
#pragma unroll
        for (int r = 0; r < 4; ++r) {
            int row = rbase + r;
            if (row < n) C[(size_t)row * HOUT + nt * 16 + col] = acc[nt][r] * dv[r];
        }
    }
}

// ---------------- final gather-aggregate (HOUT=64, no following gemm) ----------------
template<int HOUT>
__global__ __launch_bounds__(256) void agg2_k(const float* __restrict__ tmp,
                                              const int* __restrict__ csr_src,
                                              const int* __restrict__ rowptr,
                                              const float* __restrict__ dinv,
                                              const float* __restrict__ bias,
                                              float* __restrict__ out, int n) {
    constexpr int LPN = HOUT / 4;
    int gid = blockIdx.x * 256 + threadIdx.x;
    int node = gid / LPN, l = gid % LPN;
    if (node >= n) return;

    const float dn = dinv[node];
    float4 bb = *(const float4*)(bias + l * 4);
    float4 acc = *(const float4*)(tmp + (size_t)node * HOUT + l * 4);

    int e = rowptr[node];
    const int end = rowptr[node + 1];
    while (e < end) {
        int m = end - e;
        if (m > LPN) m = LPN;
        int myidx = (e + l < end) ? csr_src[e + l] : 0;
        int j = 0;
        for (; j + 4 <= m; j += 4) {
            int s0 = __shfl(myidx, j, LPN);
            int s1 = __shfl(myidx, j + 1, LPN);
            int s2 = __shfl(myidx, j + 2, LPN);
            int s3 = __shfl(myidx, j + 3, LPN);
            float4 v0 = *(const float4*)(tmp + (size_t)s0 * HOUT + l * 4);
            float4 v1 = *(const float4*)(tmp + (size_t)s1 * HOUT + l * 4);
            float4 v2 = *(const float4*)(tmp + (size_t)s2 * HOUT + l * 4);
            float4 v3 = *(const float4*)(tmp + (size_t)s3 * HOUT + l * 4);
            acc.x += (v0.x + v1.x) + (v2.x + v3.x);
            acc.y += (v0.y + v1.y) + (v2.y + v3.y);
            acc.z += (v0.z + v1.z) + (v2.z + v3.z);
            acc.w += (v0.w + v1.w) + (v2.w + v3.w);
        }
        for (; j < m; ++j) {
            int s0 = __shfl(myidx, j, LPN);
            float4 v0 = *(const float4*)(tmp + (size_t)s0 * HOUT + l * 4);
            acc.x += v0.x; acc.y += v0.y; acc.z += v0.z; acc.w += v0.w;
        }
        e += m;
    }
    float4 o;
    o.x = fmaf(acc.x, dn, bb.x);
    o.y = fmaf(acc.y, dn, bb.y);
    o.z = fmaf(acc.z, dn, bb.z);
    o.w = fmaf(acc.w, dn, bb.w);
    *(float4*)(out + (size_t)node * HOUT + l * 4) = o;
}

extern "C" void kernel_launch(void* const* d_in, const int* in_sizes, int n_in,
                              void* d_out, int out_size, void* d_ws, size_t ws_size,
                              hipStream_t stream) {
    const float* x    = (const float*)d_in[0];
    const int*   ei   = (const int*)d_in[1];
    const int*   srcp = ei;
    const int*   dstp = ei + NE;
    const float* W0 = (const float*)d_in[2]; const float* b0 = (const float*)d_in[3];
    const float* W1 = (const float*)d_in[4]; const float* b1 = (const float*)d_in[5];
    const float* W2 = (const float*)d_in[6]; const float* b2 = (const float*)d_in[7];
    const float* W3 = (const float*)d_in[8]; const float* b3 = (const float*)d_in[9];
    float* out = (float*)d_out;

    char* ws = (char*)d_ws;
    size_t off = 0;
    auto alloc = [&](size_t bytes) { void* p = ws + off; off = (off + bytes + 255) & ~(size_t)255; return p; };
    int*   hist    = (int*)alloc((size_t)NB * 4);
    int*   boff    = (int*)alloc((size_t)(NB + 1) * 4);
    int*   bcur    = (int*)alloc((size_t)NB * 4);
    float* dinv    = (float*)alloc((size_t)NN * 4);
    int*   rowptr  = (int*)alloc((size_t)(NN + 1) * 4);
    int*   csr_src = (int*)alloc((size_t)NE * 4);
    short* wt      = (short*)alloc((size_t)114688 * 2);
    float* bufA    = (float*)alloc((size_t)NN * 128 * 4);
    float* bufB    = (float*)alloc((size_t)NN * 128 * 4);
    int2*  pairs   = (int2*)bufA;   // alias: pairs dead before first gemm writes bufA

    const int nblk_e4k  = (NE + 4095) / 4096;   // 391
    const int nblk_g    = (NN + 63) / 64;       // 1563
    const int nblk_a64  = (int)(((size_t)NN * 16 + 255) / 256);

    // ---- graph preprocessing: bucketed CSR build ----
    hipMemsetAsync(hist, 0, (size_t)NB * 4, stream);
    hist_k<<<nblk_e4k, 256, 0, stream>>>(dstp, hist, NE);
    bktscan_k<<<1, 512, 0, stream>>>(hist, boff, bcur);
    part2_k<<<nblk_e4k, 256, 0, stream>>>(srcp, dstp, bcur, pairs, NE);
    cnt2_k<<<NB, 256, 0, stream>>>(pairs, boff, dinv, rowptr, NN);
    csrfill_k<<<NB, 256, 0, stream>>>(pairs, boff, rowptr, csr_src, NN);
    convw_k<<<(57344 + 255) / 256, 256, 0, stream>>>(W0, W1, W2, W3, wt);

    const short* w0h = wt,          *w0l = wt + 16384;
    const short* w1h = wt + 32768,  *w1l = wt + 49152;
    const short* w2h = wt + 65536,  *w2l = wt + 81920;
    const short* w3h = wt + 98304,  *w3l = wt + 106496;

    // layer 0 gemm: x -> tmp0 (bufB so pairs in bufA stay live until part2 done)
    mfma_gemm_k<<<nblk_g, 256, 0, stream>>>(x, w0h, w0l, dinv, bufB, NN);
    // fused layer0-agg + layer1 gemm: tmp0 -> tmp1
    fused_k<128><<<nblk_g, 256, 0, stream>>>(bufB, csr_src, rowptr, dinv, b0, w1h, w1l, bufA, NN);
    // fused layer1-agg + layer2 gemm: tmp1 -> tmp2
    fused_k<128><<<nblk_g, 256, 0, stream>>>(bufA, csr_src, rowptr, dinv, b1, w2h, w2l, bufB, NN);
    // fused layer2-agg + layer3 gemm: tmp2 -> tmp3
    fused_k<64><<<nblk_g, 256, 0, stream>>>(bufB, csr_src, rowptr, dinv, b2, w3h, w3l, bufA, NN);
    // final aggregation of tmp3 -> out
    agg2_k<64><<<nblk_a64, 256, 0, stream>>>(bufA, csr_src, rowptr, dinv, b3, out, NN);
}

// Round 7
// 634.509 us; speedup vs baseline: 2.0314x; 1.0958x over previous
//
#include <hip/hip_runtime.h>
#include <math.h>

#define NN 100000
#define NE 1600000
#define NB 391   // ceil(NN/256) dst-buckets of 256 nodes

typedef __attribute__((ext_vector_type(8))) short short8;
typedef __attribute__((ext_vector_type(4))) float f32x4;
union frag8 { short s[8]; short8 v; };

// split fp32 into bf16 hi (truncated) + bf16 lo (rounded residual)
__device__ __forceinline__ void split_bf16(float a, short& hi, short& lo) {
    unsigned u = __float_as_uint(a);
    unsigned hb = u & 0xffff0000u;
    hi = (short)(hb >> 16);
    float r = a - __uint_as_float(hb);
    unsigned lu = __float_as_uint(r);
    lo = (short)((lu + 0x7fff + ((lu >> 16) & 1)) >> 16);
}

// ---------------- bucket histogram ----------------
__global__ __launch_bounds__(256) void hist_k(const int* __restrict__ dst, int* __restrict__ hist, int e) {
    __shared__ int h[NB];
    int t = threadIdx.x;
    for (int i = t; i < NB; i += 256) h[i] = 0;
    __syncthreads();
    int base = blockIdx.x * 4096;
#pragma unroll
    for (int j = 0; j < 16; ++j) {
        int i = base + j * 256 + t;
        if (i < e) atomicAdd(&h[dst[i] >> 8], 1);
    }
    __syncthreads();
    for (int i = t; i < NB; i += 256) if (h[i]) atomicAdd(&hist[i], h[i]);
}

// ---------------- bucket scan ----------------
__global__ __launch_bounds__(512) void bktscan_k(const int* __restrict__ hist,
                                                 int* __restrict__ boff, int* __restrict__ bcur) {
    __shared__ int wsum[8];
    int t = threadIdx.x, lane = t & 63, wid = t >> 6;
    int v = (t < NB) ? hist[t] : 0;
    int inc = v;
#pragma unroll
    for (int off = 1; off < 64; off <<= 1) {
        int tt = __shfl_up(inc, off);
        if (lane >= off) inc += tt;
    }
    if (lane == 63) wsum[wid] = inc;
    __syncthreads();
    int woff = 0;
    for (int w = 0; w < wid; ++w) woff += wsum[w];
    int excl = inc - v + woff;
    if (t < NB) { boff[t] = excl; bcur[t] = excl; }
    if (t == NB - 1) boff[NB] = excl + v;
}

// ---------------- partition via block-local chunk reservation ----------------
__global__ __launch_bounds__(256) void part2_k(const int* __restrict__ src, const int* __restrict__ dst,
                                               int* bcur, int2* __restrict__ pairs, int e) {
    __shared__ int lhist[NB];
    __shared__ int lbase[NB];
    int t = threadIdx.x;
    for (int i = t; i < NB; i += 256) lhist[i] = 0;
    __syncthreads();
    int e0 = blockIdx.x * 4096;
    int sreg[16], dreg[16];
#pragma unroll
    for (int j = 0; j < 16; ++j) {
        int i = e0 + j * 256 + t;
        if (i < e) {
            sreg[j] = src[i];
            dreg[j] = dst[i];
            atomicAdd(&lhist[dreg[j] >> 8], 1);
        } else dreg[j] = -1;
    }
    __syncthreads();
    for (int i = t; i < NB; i += 256) {
        int c = lhist[i];
        lbase[i] = c ? atomicAdd(&bcur[i], c) : 0;
        lhist[i] = 0;
    }
    __syncthreads();
#pragma unroll
    for (int j = 0; j < 16; ++j) {
        if (dreg[j] >= 0) {
            int b = dreg[j] >> 8;
            int pos = lbase[b] + atomicAdd(&lhist[b], 1);
            pairs[pos] = make_int2(sreg[j], dreg[j]);
        }
    }
}

// ---------------- per-bucket: count, dinv, rowptr ----------------
__global__ __launch_bounds__(256) void cnt2_k(const int2* __restrict__ pairs, const int* __restrict__ boff,
                                              float* __restrict__ dinv, int* __restrict__ rowptr, int n) {
    __shared__ int cnt[256];
    __shared__ int wsum[4];
    int b = blockIdx.x, t = threadIdx.x;
    cnt[t] = 0;
    __syncthreads();
    int e0 = boff[b], e1 = boff[b + 1];
    for (int e = e0 + t; e < e1; e += 256) atomicAdd(&cnt[pairs[e].y & 255], 1);
    __syncthreads();
    int c = cnt[t];
    int lane = t & 63, wid = t >> 6;
    int inc = c;
#pragma unroll
    for (int off = 1; off < 64; off <<= 1) {
        int tt = __shfl_up(inc, off);
        if (lane >= off) inc += tt;
    }
    if (lane == 63) wsum[wid] = inc;
    __syncthreads();
    int woff = 0;
    for (int w = 0; w < wid; ++w) woff += wsum[w];
    int excl = inc - c + woff + e0;
    int i = (b << 8) + t;
    if (i < n) {
        rowptr[i] = excl;
        dinv[i] = 1.0f / sqrtf((float)(c + 1));
    }
    if (b == NB - 1 && t == 255) rowptr[n] = e1;
}

// ---------------- per-bucket CSR fill ----------------
__global__ __launch_bounds__(256) void csrfill_k(const int2* __restrict__ pairs, const int* __restrict__ boff,
                                                 const int* __restrict__ rowptr, int* __restrict__ csr_src, int n) {
    __shared__ int lcur[256];
    int b = blockIdx.x, t = threadIdx.x;
    int i = (b << 8) + t;
    lcur[t] = (i < n) ? rowptr[i] : 0;
    __syncthreads();
    int e0 = boff[b], e1 = boff[b + 1];
    for (int e = e0 + t; e < e1; e += 256) {
        int2 p = pairs[e];
        int pos = atomicAdd(&lcur[p.y & 255], 1);
        csr_src[pos] = p.x;
    }
}

// ---------------- W pre-split (transposed bf16 hi/lo) ----------------
__global__ __launch_bounds__(256) void convw_k(const float* __restrict__ W0, const float* __restrict__ W1,
                                               const float* __restrict__ W2, const float* __restrict__ W3,
                                               short* __restrict__ wt) {
    int gid = blockIdx.x * 256 + threadIdx.x;
    if (gid >= 57344) return;
    const float* W;
    int elem, Ncols, hi_base;
    if (gid < 49152) {
        int w = gid >> 14;
        elem = gid & 16383;
        Ncols = 128;
        W = (w == 0) ? W0 : (w == 1) ? W1 : W2;
        hi_base = w * 32768;
    } else {
        elem = gid - 49152;
        Ncols = 64;
        W = W3;
        hi_base = 98304;
    }
    int k = elem / Ncols, ncol = elem % Ncols;
    short hi, lo;
    split_bf16(W[elem], hi, lo);
    int dstidx = ncol * 128 + k;
    wt[hi_base + dstidx] = hi;
    wt[hi_base + Ncols * 128 + dstidx] = lo;
}

// ---------------- MFMA GEMM (layer 0): C = (x @ W)·dinv ----------------
__global__ __launch_bounds__(256) void mfma_gemm_k(const float* __restrict__ A,
                                                   const short* __restrict__ wt_hi,
                                                   const short* __restrict__ wt_lo,
                                                   const float* __restrict__ dinv,
                                                   float* __restrict__ C, int n) {
    constexpr int NT = 8;
    const int tid = threadIdx.x;
    const int wid = tid >> 6, lane = tid & 63;
    const int arow = blockIdx.x * 64 + wid * 16 + (lane & 15);
    const int khalf = lane >> 4;

    f32x4 acc[NT];
#pragma unroll
    for (int nt = 0; nt < NT; ++nt) acc[nt] = (f32x4){0.f, 0.f, 0.f, 0.f};

#pragma unroll
    for (int kc = 0; kc < 4; ++kc) {
        const int k0 = kc * 32 + khalf * 8;
        float4 a0 = make_float4(0.f, 0.f, 0.f, 0.f), a1 = a0;
        if (arow < n) {
            a0 = *(const float4*)(A + (size_t)arow * 128 + k0);
            a1 = *(const float4*)(A + (size_t)arow * 128 + k0 + 4);
        }
        frag8 ahi, alo;
        float av[8] = {a0.x, a0.y, a0.z, a0.w, a1.x, a1.y, a1.z, a1.w};
#pragma unroll
        for (int j = 0; j < 8; ++j) split_bf16(av[j], ahi.s[j], alo.s[j]);

#pragma unroll
        for (int nt = 0; nt < NT; ++nt) {
            const size_t bidx = (size_t)(nt * 16 + (lane & 15)) * 128 + k0;
            short8 bhi = *(const short8*)(wt_hi + bidx);
            short8 blo = *(const short8*)(wt_lo + bidx);
            acc[nt] = __builtin_amdgcn_mfma_f32_16x16x32_bf16(alo.v, bhi, acc[nt], 0, 0, 0);
            acc[nt] = __builtin_amdgcn_mfma_f32_16x16x32_bf16(ahi.v, blo, acc[nt], 0, 0, 0);
            acc[nt] = __builtin_amdgcn_mfma_f32_16x16x32_bf16(ahi.v, bhi, acc[nt], 0, 0, 0);
        }
    }

    const int rbase = blockIdx.x * 64 + wid * 16 + khalf * 4;
    const int col = lane & 15;
    float dv[4];
#pragma unroll
    for (int r = 0; r < 4; ++r) dv[r] = (rbase + r < n) ? dinv[rbase + r] : 0.f;
#pragma unroll
    for (int nt = 0; nt < NT; ++nt) {
#pragma unroll
        for (int r = 0; r < 4; ++r) {
            int row = rbase + r;
            if (row < n) C[(size_t)row * 128 + nt * 16 + col] = acc[nt][r] * dv[r];
        }
    }
}

// ---------------- FUSED v2: 32-row tile (16.9 KB LDS -> 8 blocks/CU) ----------------
// phase 1: aggregate 32 nodes into LDS; phase 2: split-bf16 MFMA from LDS
// wave w: row-tile rt=w&1, col-group cg=w>>1 covering NT=HOUT/32 col-tiles
template<int HOUT>
__global__ __launch_bounds__(256) void fused_k(const float* __restrict__ tmp,
                                               const int* __restrict__ csr_src,
                                               const int* __restrict__ rowptr,
                                               const float* __restrict__ dinv,
                                               const float* __restrict__ bias,
                                               const short* __restrict__ wt_hi,
                                               const short* __restrict__ wt_lo,
                                               float* __restrict__ C, int n) {
    constexpr int NT = HOUT / 32;
    __shared__ float As[32][132];
    const int t = threadIdx.x;
    const int row0 = blockIdx.x * 32;

    // ---- phase 1: 8 groups of 32 lanes, 4 passes of 8 nodes ----
    {
        const int l = t & 31;
        const int sub = t >> 5;
        float4 bb = *(const float4*)(bias + l * 4);
#pragma unroll
        for (int it = 0; it < 4; ++it) {
            int node = row0 + it * 8 + sub;
            float4 acc = make_float4(0.f, 0.f, 0.f, 0.f);
            if (node < n) {
                float dn = dinv[node];
                acc = *(const float4*)(tmp + (size_t)node * 128 + l * 4);
                int e = rowptr[node];
                const int end = rowptr[node + 1];
                while (e < end) {
                    int m = end - e;
                    if (m > 32) m = 32;
                    int myidx = (e + l < end) ? csr_src[e + l] : 0;
                    int j = 0;
                    for (; j + 4 <= m; j += 4) {
                        int s0 = __shfl(myidx, j, 32);
                        int s1 = __shfl(myidx, j + 1, 32);
                        int s2 = __shfl(myidx, j + 2, 32);
                        int s3 = __shfl(myidx, j + 3, 32);
                        float4 v0 = *(const float4*)(tmp + (size_t)s0 * 128 + l * 4);
                        float4 v1 = *(const float4*)(tmp + (size_t)s1 * 128 + l * 4);
                        float4 v2 = *(const float4*)(tmp + (size_t)s2 * 128 + l * 4);
                        float4 v3 = *(const float4*)(tmp + (size_t)s3 * 128 + l * 4);
                        acc.x += (v0.x + v1.x) + (v2.x + v3.x);
                        acc.y += (v0.y + v1.y) + (v2.y + v3.y);
                        acc.z += (v0.z + v1.z) + (v2.z + v3.z);
                        acc.w += (v0.w + v1.w) + (v2.w + v3.w);
                    }
                    for (; j < m; ++j) {
                        int s0 = __shfl(myidx, j, 32);
                        float4 v0 = *(const float4*)(tmp + (size_t)s0 * 128 + l * 4);
                        acc.x += v0.x; acc.y += v0.y; acc.z += v0.z; acc.w += v0.w;
                    }
                    e += m;
                }
                acc.x = fmaxf(fmaf(acc.x, dn, bb.x), 0.f);
                acc.y = fmaxf(fmaf(acc.y, dn, bb.y), 0.f);
                acc.z = fmaxf(fmaf(acc.z, dn, bb.z), 0.f);
                acc.w = fmaxf(fmaf(acc.w, dn, bb.w), 0.f);
            }
            *(float4*)&As[it * 8 + sub][l * 4] = acc;
        }
    }
    __syncthreads();

    // ---- phase 2: MFMA from LDS ----
    const int wid = t >> 6, lane = t & 63;
    const int rt = wid & 1;          // row-tile 0..1
    const int cg = wid >> 1;         // col-group 0..1
    const int arow_l = rt * 16 + (lane & 15);
    const int khalf = lane >> 4;

    f32x4 acc[NT];
#pragma unroll
    for (int nt = 0; nt < NT; ++nt) acc[nt] = (f32x4){0.f, 0.f, 0.f, 0.f};

#pragma unroll
    for (int kc = 0; kc < 4; ++kc) {
        const int k0 = kc * 32 + khalf * 8;
        float4 a0 = *(const float4*)&As[arow_l][k0];
        float4 a1 = *(const float4*)&As[arow_l][k0 + 4];
        frag8 ahi, alo;
        float av[8] = {a0.x, a0.y, a0.z, a0.w, a1.x, a1.y, a1.z, a1.w};
#pragma unroll
        for (int j = 0; j < 8; ++j) split_bf16(av[j], ahi.s[j], alo.s[j]);

#pragma unroll
        for (int nt = 0; nt < NT; ++nt) {
            const size_t bidx = (size_t)(cg * NT * 16 + nt * 16 + (lane & 15)) * 128 + k0;
            short8 bhi = *(const short8*)(wt_hi + bidx);
            short8 blo = *(const short8*)(wt_lo + bidx);
            acc[nt] = __builtin_amdgcn_mfma_f32_16x16x32_bf16(alo.v, bhi, acc[nt], 0, 0, 0);
            acc[nt] = __builtin_amdgcn_mfma_f32_16x16x32_bf16(ahi.v, blo, acc[nt], 0, 0, 0);
            acc[nt] = __builtin_amdgcn_mfma_f32_16x16x32_bf16(ahi.v, bhi, acc[nt], 0, 0, 0);
        }
    }

    const int rbase = row0 + rt * 16 + khalf * 4;
    const int col = lane & 15;
    float dv[4];
#pragma unroll
    for (int r = 0; r < 4; ++r) dv[r] = (rbase + r < n) ? dinv[rbase + r] : 0.f;
#pragma unroll
    for (int nt = 0; nt < NT; ++nt) {
#pragma unroll
        for (int r = 0; r < 4; ++r) {
            int row = rbase + r;
            if (row < n) C[(size_t)row * HOUT + cg * NT * 16 + nt * 16 + col] = acc[nt][r] * dv[r];
        }
    }
}

// ---------------- final gather-aggregate (HOUT=64) ----------------
template<int HOUT>
__global__ __launch_bounds__(256) void agg2_k(const float* __restrict__ tmp,
                                              const int* __restrict__ csr_src,
                                              const int* __restrict__ rowptr,
                                              const float* __restrict__ dinv,
                                              const float* __restrict__ bias,
                                              float* __restrict__ out, int n) {
    constexpr int LPN = HOUT / 4;
    int gid = blockIdx.x * 256 + threadIdx.x;
    int node = gid / LPN, l = gid % LPN;
    if (node >= n) return;

    const float dn = dinv[node];
    float4 bb = *(const float4*)(bias + l * 4);
    float4 acc = *(const float4*)(tmp + (size_t)node * HOUT + l * 4);

    int e = rowptr[node];
    const int end = rowptr[node + 1];
    while (e < end) {
        int m = end - e;
        if (m > LPN) m = LPN;
        int myidx = (e + l < end) ? csr_src[e + l] : 0;
        int j = 0;
        for (; j + 4 <= m; j += 4) {
            int s0 = __shfl(myidx, j, LPN);
            int s1 = __shfl(myidx, j + 1, LPN);
            int s2 = __shfl(myidx, j + 2, LPN);
            int s3 = __shfl(myidx, j + 3, LPN);
            float4 v0 = *(const float4*)(tmp + (size_t)s0 * HOUT + l * 4);
            float4 v1 = *(const float4*)(tmp + (size_t)s1 * HOUT + l * 4);
            float4 v2 = *(const float4*)(tmp + (size_t)s2 * HOUT + l * 4);
            float4 v3 = *(const float4*)(tmp + (size_t)s3 * HOUT + l * 4);
            acc.x += (v0.x + v1.x) + (v2.x + v3.x);
            acc.y += (v0.y + v1.y) + (v2.y + v3.y);
            acc.z += (v0.z + v1.z) + (v2.z + v3.z);
            acc.w += (v0.w + v1.w) + (v2.w + v3.w);
        }
        for (; j < m; ++j) {
            int s0 = __shfl(myidx, j, LPN);
            float4 v0 = *(const float4*)(tmp + (size_t)s0 * HOUT + l * 4);
            acc.x += v0.x; acc.y += v0.y; acc.z += v0.z; acc.w += v0.w;
        }
        e += m;
    }
    float4 o;
    o.x = fmaf(acc.x, dn, bb.x);
    o.y = fmaf(acc.y, dn, bb.y);
    o.z = fmaf(acc.z, dn, bb.z);
    o.w = fmaf(acc.w, dn, bb.w);
    *(float4*)(out + (size_t)node * HOUT + l * 4) = o;
}

extern "C" void kernel_launch(void* const* d_in, const int* in_sizes, int n_in,
                              void* d_out, int out_size, void* d_ws, size_t ws_size,
                              hipStream_t stream) {
    const float* x    = (const float*)d_in[0];
    const int*   ei   = (const int*)d_in[1];
    const int*   srcp = ei;
    const int*   dstp = ei + NE;
    const float* W0 = (const float*)d_in[2]; const float* b0 = (const float*)d_in[3];
    const float* W1 = (const float*)d_in[4]; const float* b1 = (const float*)d_in[5];
    const float* W2 = (const float*)d_in[6]; const float* b2 = (const float*)d_in[7];
    const float* W3 = (const float*)d_in[8]; const float* b3 = (const float*)d_in[9];
    float* out = (float*)d_out;

    char* ws = (char*)d_ws;
    size_t off = 0;
    auto alloc = [&](size_t bytes) { void* p = ws + off; off = (off + bytes + 255) & ~(size_t)255; return p; };
    int*   hist    = (int*)alloc((size_t)NB * 4);
    int*   boff    = (int*)alloc((size_t)(NB + 1) * 4);
    int*   bcur    = (int*)alloc((size_t)NB * 4);
    float* dinv    = (float*)alloc((size_t)NN * 4);
    int*   rowptr  = (int*)alloc((size_t)(NN + 1) * 4);
    int*   csr_src = (int*)alloc((size_t)NE * 4);
    short* wt      = (short*)alloc((size_t)114688 * 2);
    float* bufA    = (float*)alloc((size_t)NN * 128 * 4);
    float* bufB    = (float*)alloc((size_t)NN * 128 * 4);
    int2*  pairs   = (int2*)bufA;   // alias: pairs dead before first gemm writes bufA

    const int nblk_e4k  = (NE + 4095) / 4096;   // 391
    const int nblk_g    = (NN + 63) / 64;       // 1563
    const int nblk_f    = (NN + 31) / 32;       // 3125
    const int nblk_a64  = (int)(((size_t)NN * 16 + 255) / 256);

    // ---- graph preprocessing: bucketed CSR build ----
    hipMemsetAsync(hist, 0, (size_t)NB * 4, stream);
    hist_k<<<nblk_e4k, 256, 0, stream>>>(dstp, hist, NE);
    bktscan_k<<<1, 512, 0, stream>>>(hist, boff, bcur);
    part2_k<<<nblk_e4k, 256, 0, stream>>>(srcp, dstp, bcur, pairs, NE);
    cnt2_k<<<NB, 256, 0, stream>>>(pairs, boff, dinv, rowptr, NN);
    csrfill_k<<<NB, 256, 0, stream>>>(pairs, boff, rowptr, csr_src, NN);
    convw_k<<<(57344 + 255) / 256, 256, 0, stream>>>(W0, W1, W2, W3, wt);

    const short* w0h = wt,          *w0l = wt + 16384;
    const short* w1h = wt + 32768,  *w1l = wt + 49152;
    const short* w2h = wt + 65536,  *w2l = wt + 81920;
    const short* w3h = wt + 98304,  *w3l = wt + 106496;

    // layer 0 gemm: x -> tmp0 (bufB so pairs in bufA stay live until part2 done)
    mfma_gemm_k<<<nblk_g, 256, 0, stream>>>(x, w0h, w0l, dinv, bufB, NN);
    // fused layer0-agg + layer1 gemm: tmp0 -> tmp1
    fused_k<128><<<nblk_f, 256, 0, stream>>>(bufB, csr_src, rowptr, dinv, b0, w1h, w1l, bufA, NN);
    // fused layer1-agg + layer2 gemm: tmp1 -> tmp2
    fused_k<128><<<nblk_f, 256, 0, stream>>>(bufA, csr_src, rowptr, dinv, b1, w2h, w2l, bufB, NN);
    // fused layer2-agg + layer3 gemm: tmp2 -> tmp3
    fused_k<64><<<nblk_f, 256, 0, stream>>>(bufB, csr_src, rowptr, dinv, b2, w3h, w3l, bufA, NN);
    // final aggregation of tmp3 -> out
    agg2_k<64><<<nblk_a64, 256, 0, stream>>>(bufA, csr_src, rowptr, dinv, b3, out, NN);
}